// Round 1
// baseline (723.698 us; speedup 1.0000x reference)
//
#include <hip/hip_runtime.h>
#include <hip/hip_bf16.h>

// FeatureAttention on MI355X — Round 1: correct bf16-MFMA baseline.
// B=32 E=16 F=64 D=512 EXP=4. Rows M = B*E*F = 32768.
// Pipeline: wconv(x5) -> LN1 -> GEMM q,k,v -> attn(block per (b,e)) -> LN2
//           -> FFN1 -> FFN2(+bias+residual).
// ws layout: h/h2 @0 (32MB), q@32MB k@64MB v@96MB (ff1 @32MB aliases dead qkv,
// 128MB), bf16 transposed weights @160MB (~5.8MB). Total ~166MB.

#define D_DIM 512
#define NROWS 32768
#define NBE   512

typedef __attribute__((ext_vector_type(8))) short bf16x8;
typedef __attribute__((ext_vector_type(4))) float f32x4;

__device__ __forceinline__ short f2bf(float f) {
  union { float f; unsigned u; } c; c.f = f;
  unsigned u = c.u;
  unsigned r = (u + 0x7FFFu + ((u >> 16) & 1u)) >> 16;   // RNE
  return (short)r;
}
__device__ __forceinline__ float bf2f(short s) {
  union { unsigned u; float f; } c; c.u = ((unsigned)(unsigned short)s) << 16;
  return c.f;
}

// ---- transpose + fp32->bf16 weight convert: Wt[n*K+k] = W[k*N+n] ----
__global__ __launch_bounds__(256) void wconv_kernel(const float* __restrict__ W,
                                                    short* __restrict__ Wt,
                                                    int K, int N) {
  long idx = (long)blockIdx.x * 256 + threadIdx.x;
  if (idx >= (long)K * N) return;
  int n = (int)(idx / K);
  int k = (int)(idx % K);
  Wt[idx] = f2bf(W[(long)k * N + n]);      // coalesced writes, strided reads
}

// ---- LayerNorm over D=512, fp32 in -> bf16 out. One wave per row. ----
__global__ __launch_bounds__(256) void ln_kernel(const float* __restrict__ x,
                                                 const float* __restrict__ gam,
                                                 const float* __restrict__ bet,
                                                 short* __restrict__ h) {
  const int t = threadIdx.x;
  const long row = (long)blockIdx.x * 4 + (t >> 6);
  const int lane = t & 63;
  const float* xr = x + row * D_DIM + lane * 8;
  float4 a = *(const float4*)xr;
  float4 b = *(const float4*)(xr + 4);
  float xs[8] = {a.x, a.y, a.z, a.w, b.x, b.y, b.z, b.w};
  float s = 0.f, ss = 0.f;
#pragma unroll
  for (int j = 0; j < 8; ++j) { s += xs[j]; ss += xs[j] * xs[j]; }
#pragma unroll
  for (int m = 1; m < 64; m <<= 1) {
    s  += __shfl_xor(s, m);
    ss += __shfl_xor(ss, m);
  }
  float mean = s * (1.f / D_DIM);
  float var  = ss * (1.f / D_DIM) - mean * mean;
  float rstd = rsqrtf(var + 1e-5f);
  union { short sh[8]; int4 v; } o;
#pragma unroll
  for (int j = 0; j < 8; ++j) {
    int d = lane * 8 + j;
    o.sh[j] = f2bf((xs[j] - mean) * rstd * gam[d] + bet[d]);
  }
  *(int4*)&h[row * D_DIM + lane * 8] = o.v;
}

// ---- bf16 MFMA GEMM: out[M,N] = A[M,K] @ Bt[N,K]^T + bias (+resid) ----
// 64x64 tile / block (4 waves, one 16-row strip each), BK=32.
template <int OUT_BF16, int RESID>
__global__ __launch_bounds__(256) void gemm_kernel(
    const short* __restrict__ A, const short* __restrict__ Bt,
    const float* __restrict__ bias, const float* __restrict__ resid,
    void* __restrict__ outp, int M, int N, int K) {
  __shared__ short As[64][32];
  __shared__ short Bs[64][32];
  const int t = threadIdx.x;
  const int wave = t >> 6, lane = t & 63;
  const int lr = lane & 15, g = lane >> 4;
  const int m0 = blockIdx.y * 64, n0 = blockIdx.x * 64;
  const int sr = t >> 2, sc = (t & 3) * 8;
  const f32x4 vzero = {0.f, 0.f, 0.f, 0.f};
  f32x4 acc[4];
#pragma unroll
  for (int nt = 0; nt < 4; ++nt) acc[nt] = vzero;

  for (int k0 = 0; k0 < K; k0 += 32) {
    *(int4*)&As[sr][sc] = *(const int4*)&A[(long)(m0 + sr) * K + k0 + sc];
    *(int4*)&Bs[sr][sc] = *(const int4*)&Bt[(long)(n0 + sr) * K + k0 + sc];
    __syncthreads();
    bf16x8 afr = *(const bf16x8*)&As[wave * 16 + lr][g * 8];
#pragma unroll
    for (int nt = 0; nt < 4; ++nt) {
      bf16x8 bfr = *(const bf16x8*)&Bs[nt * 16 + lr][g * 8];
      acc[nt] = __builtin_amdgcn_mfma_f32_16x16x32_bf16(afr, bfr, acc[nt], 0, 0, 0);
    }
    __syncthreads();
  }
  // D layout: row = 4*(lane>>4)+reg (within wave strip), col = lane&15
#pragma unroll
  for (int nt = 0; nt < 4; ++nt) {
    int col = n0 + nt * 16 + lr;
    float bv = bias[col];
#pragma unroll
    for (int r = 0; r < 4; ++r) {
      long row = m0 + wave * 16 + 4 * g + r;
      float val = acc[nt][r] + bv;
      if (RESID) val += resid[row * (long)N + col];
      if (OUT_BF16) ((short*)outp)[row * (long)N + col] = f2bf(val);
      else          ((float*)outp)[row * (long)N + col] = val;
    }
  }
}

// ---- fused feature attention, one block per (b,e): 64 q-rows ----
// energy = q@k^T (MFMA, frags straight from global/L2), LN over keys,
// softmax/sqrt(D), PV on VALU (v from L2), + residual x -> x1.
__global__ __launch_bounds__(256) void attn_kernel(
    const short* __restrict__ q, const short* __restrict__ k,
    const short* __restrict__ v, const float* __restrict__ x,
    const float* __restrict__ wn_g, const float* __restrict__ wn_b,
    float* __restrict__ x1) {
  __shared__ float att_s[64][68];        // 68: keep float4 rows 16B-aligned
  const int t = threadIdx.x;
  const int wave = t >> 6, lane = t & 63;
  const int lr = lane & 15, g = lane >> 4;
  const long base = (long)blockIdx.x * 64;
  const long qoff = base * D_DIM;

  const f32x4 vzero = {0.f, 0.f, 0.f, 0.f};
  f32x4 acc[4];
#pragma unroll
  for (int nt = 0; nt < 4; ++nt) acc[nt] = vzero;

  for (int ks = 0; ks < 16; ++ks) {
    const int kc = ks * 32 + g * 8;
    bf16x8 afr = *(const bf16x8*)&q[qoff + (long)(wave * 16 + lr) * D_DIM + kc];
#pragma unroll
    for (int nt = 0; nt < 4; ++nt) {
      bf16x8 bfr = *(const bf16x8*)&k[qoff + (long)(nt * 16 + lr) * D_DIM + kc];
      acc[nt] = __builtin_amdgcn_mfma_f32_16x16x32_bf16(afr, bfr, acc[nt], 0, 0, 0);
    }
  }

  const float scale = 0.044194173824159216f;  // 1/sqrt(512)
#pragma unroll
  for (int r = 0; r < 4; ++r) {
    // row = wave*16 + 4*g + r lives in 16 lanes (lr) x 4 regs (nt)
    float s = 0.f, ss = 0.f;
#pragma unroll
    for (int nt = 0; nt < 4; ++nt) { float e = acc[nt][r]; s += e; ss += e * e; }
#pragma unroll
    for (int m = 1; m < 16; m <<= 1) { s += __shfl_xor(s, m); ss += __shfl_xor(ss, m); }
    float mean = s * (1.f / 64);
    float var  = ss * (1.f / 64) - mean * mean;
    float rstd = rsqrtf(var + 1e-5f);
    float e[4]; float mx = -1e30f;
#pragma unroll
    for (int nt = 0; nt < 4; ++nt) {
      int col = nt * 16 + lr;
      e[nt] = ((acc[nt][r] - mean) * rstd * wn_g[col] + wn_b[col]) * scale;
      mx = fmaxf(mx, e[nt]);
    }
#pragma unroll
    for (int m = 1; m < 16; m <<= 1) mx = fmaxf(mx, __shfl_xor(mx, m));
    float se = 0.f;
#pragma unroll
    for (int nt = 0; nt < 4; ++nt) { e[nt] = expf(e[nt] - mx); se += e[nt]; }
#pragma unroll
    for (int m = 1; m < 16; m <<= 1) se += __shfl_xor(se, m);
    float inv = 1.f / se;
#pragma unroll
    for (int nt = 0; nt < 4; ++nt)
      att_s[wave * 16 + 4 * g + r][nt * 16 + lr] = e[nt] * inv;
  }
  __syncthreads();

  // PV: wave w handles q-rows w*16..w*16+15; lane owns d0 = lane*8 (8 outs/row)
  const int d0 = lane * 8;
  float accp[16][8];
#pragma unroll
  for (int qi = 0; qi < 16; ++qi)
#pragma unroll
    for (int j = 0; j < 8; ++j) accp[qi][j] = 0.f;

  for (int kk0 = 0; kk0 < 64; kk0 += 4) {
    float vf[4][8];
#pragma unroll
    for (int kc = 0; kc < 4; ++kc) {
      bf16x8 vv = *(const bf16x8*)&v[qoff + (long)(kk0 + kc) * D_DIM + d0];
#pragma unroll
      for (int j = 0; j < 8; ++j) vf[kc][j] = bf2f(vv[j]);
    }
#pragma unroll
    for (int qi = 0; qi < 16; ++qi) {
      float4 a4 = *(const float4*)&att_s[wave * 16 + qi][kk0];
#pragma unroll
      for (int j = 0; j < 8; ++j) {
        accp[qi][j] += a4.x * vf[0][j];
        accp[qi][j] += a4.y * vf[1][j];
        accp[qi][j] += a4.z * vf[2][j];
        accp[qi][j] += a4.w * vf[3][j];
      }
    }
  }
#pragma unroll
  for (int qi = 0; qi < 16; ++qi) {
    long row = base + wave * 16 + qi;
    const float* xr = x + row * D_DIM + d0;
    float* po = x1 + row * D_DIM + d0;
    float4 x0 = *(const float4*)xr;
    float4 xb = *(const float4*)(xr + 4);
    float4 o0, o1;
    o0.x = x0.x + accp[qi][0]; o0.y = x0.y + accp[qi][1];
    o0.z = x0.z + accp[qi][2]; o0.w = x0.w + accp[qi][3];
    o1.x = xb.x + accp[qi][4]; o1.y = xb.y + accp[qi][5];
    o1.z = xb.z + accp[qi][6]; o1.w = xb.w + accp[qi][7];
    *(float4*)po = o0;
    *(float4*)(po + 4) = o1;
  }
}

extern "C" void kernel_launch(void* const* d_in, const int* in_sizes, int n_in,
                              void* d_out, int out_size, void* d_ws, size_t ws_size,
                              hipStream_t stream) {
  (void)in_sizes; (void)n_in; (void)out_size; (void)ws_size;
  const float* x     = (const float*)d_in[0];
  const float* ln1_g = (const float*)d_in[1];
  const float* ln1_b = (const float*)d_in[2];
  const float* Wq    = (const float*)d_in[3];
  const float* bq    = (const float*)d_in[4];
  const float* Wk    = (const float*)d_in[5];
  const float* bk    = (const float*)d_in[6];
  const float* Wv    = (const float*)d_in[7];
  const float* bv    = (const float*)d_in[8];
  const float* wn_g  = (const float*)d_in[9];
  const float* wn_b  = (const float*)d_in[10];
  const float* ln2_g = (const float*)d_in[11];
  const float* ln2_b = (const float*)d_in[12];
  const float* W1    = (const float*)d_in[13];
  const float* b1    = (const float*)d_in[14];
  const float* W2    = (const float*)d_in[15];
  const float* b2    = (const float*)d_in[16];
  float* out = (float*)d_out;

  char* ws = (char*)d_ws;
  short* h   = (short*)(ws);                                  // 32 MB (h, then h2)
  short* qb  = (short*)(ws + (size_t)32  * 1024 * 1024);      // 32 MB
  short* kb  = (short*)(ws + (size_t)64  * 1024 * 1024);      // 32 MB
  short* vb  = (short*)(ws + (size_t)96  * 1024 * 1024);      // 32 MB
  short* ff1 = (short*)(ws + (size_t)32  * 1024 * 1024);      // 128 MB, aliases dead q/k/v
  short* Wqt = (short*)(ws + (size_t)160 * 1024 * 1024);
  short* Wkt = Wqt + 512 * 512;
  short* Wvt = Wkt + 512 * 512;
  short* W1t = Wvt + 512 * 512;                               // [2048][512]
  short* W2t = W1t + 512 * 2048;                              // [512][2048]

  // weights -> bf16, transposed to [N][K]
  wconv_kernel<<<(512 * 512)  / 256, 256, 0, stream>>>(Wq, Wqt, 512, 512);
  wconv_kernel<<<(512 * 512)  / 256, 256, 0, stream>>>(Wk, Wkt, 512, 512);
  wconv_kernel<<<(512 * 512)  / 256, 256, 0, stream>>>(Wv, Wvt, 512, 512);
  wconv_kernel<<<(512 * 2048) / 256, 256, 0, stream>>>(W1, W1t, 512, 2048);
  wconv_kernel<<<(2048 * 512) / 256, 256, 0, stream>>>(W2, W2t, 2048, 512);

  ln_kernel<<<NROWS / 4, 256, 0, stream>>>(x, ln1_g, ln1_b, h);

  dim3 g512(512 / 64, NROWS / 64);     // (8, 512)
  gemm_kernel<1, 0><<<g512, 256, 0, stream>>>(h, Wqt, bq, nullptr, qb, NROWS, 512, 512);
  gemm_kernel<1, 0><<<g512, 256, 0, stream>>>(h, Wkt, bk, nullptr, kb, NROWS, 512, 512);
  gemm_kernel<1, 0><<<g512, 256, 0, stream>>>(h, Wvt, bv, nullptr, vb, NROWS, 512, 512);

  attn_kernel<<<NBE, 256, 0, stream>>>(qb, kb, vb, x, wn_g, wn_b, out);

  ln_kernel<<<NROWS / 4, 256, 0, stream>>>(out, ln2_g, ln2_b, h);   // h2

  dim3 g2048(2048 / 64, NROWS / 64);   // (32, 512)
  gemm_kernel<1, 0><<<g2048, 256, 0, stream>>>(h, W1t, b1, nullptr, ff1, NROWS, 2048, 512);
  gemm_kernel<0, 1><<<g512,  256, 0, stream>>>(ff1, W2t, b2, out, out, NROWS, 512, 2048);
}

// Round 2
// 606.875 us; speedup vs baseline: 1.1925x; 1.1925x over previous
//
#include <hip/hip_runtime.h>
#include <hip/hip_bf16.h>

// FeatureAttention on MI355X — Round 2: m97-structure GEMMs.
// B=32 E=16 F=64 D=512 EXP=4. Rows M = B*E*F = 32768.
// Pipeline: wconv(x5) -> LN1 -> fused QKV GEMM -> attn -> LN2 -> FFN1 -> FFN2.
// GEMM: 128x128 tile, BK=32, 4 waves (2x2, 64x64 each), global_load_lds w=16.

#define D_DIM 512
#define NROWS 32768
#define NBE   512

typedef __attribute__((ext_vector_type(8))) short bf16x8;
typedef __attribute__((ext_vector_type(4))) float f32x4;

typedef const __attribute__((address_space(1))) unsigned g_u32;
typedef __attribute__((address_space(3))) unsigned lds_u32;

__device__ __forceinline__ short f2bf(float f) {
  union { float f; unsigned u; } c; c.f = f;
  unsigned u = c.u;
  unsigned r = (u + 0x7FFFu + ((u >> 16) & 1u)) >> 16;   // RNE
  return (short)r;
}
__device__ __forceinline__ float bf2f(short s) {
  union { unsigned u; float f; } c; c.u = ((unsigned)(unsigned short)s) << 16;
  return c.f;
}

// ---- transpose + fp32->bf16 weight convert: Wt[n*K+k] = W[k*N+n] ----
__global__ __launch_bounds__(256) void wconv_kernel(const float* __restrict__ W,
                                                    short* __restrict__ Wt,
                                                    int K, int N) {
  long idx = (long)blockIdx.x * 256 + threadIdx.x;
  if (idx >= (long)K * N) return;
  int n = (int)(idx / K);
  int k = (int)(idx % K);
  Wt[idx] = f2bf(W[(long)k * N + n]);      // coalesced writes, strided reads
}

// ---- LayerNorm over D=512, fp32 in -> bf16 out. One wave per row. ----
__global__ __launch_bounds__(256) void ln_kernel(const float* __restrict__ x,
                                                 const float* __restrict__ gam,
                                                 const float* __restrict__ bet,
                                                 short* __restrict__ h) {
  const int t = threadIdx.x;
  const long row = (long)blockIdx.x * 4 + (t >> 6);
  const int lane = t & 63;
  const float* xr = x + row * D_DIM + lane * 8;
  float4 a = *(const float4*)xr;
  float4 b = *(const float4*)(xr + 4);
  float xs[8] = {a.x, a.y, a.z, a.w, b.x, b.y, b.z, b.w};
  float s = 0.f, ss = 0.f;
#pragma unroll
  for (int j = 0; j < 8; ++j) { s += xs[j]; ss += xs[j] * xs[j]; }
#pragma unroll
  for (int m = 1; m < 64; m <<= 1) {
    s  += __shfl_xor(s, m);
    ss += __shfl_xor(ss, m);
  }
  float mean = s * (1.f / D_DIM);
  float var  = ss * (1.f / D_DIM) - mean * mean;
  float rstd = rsqrtf(var + 1e-5f);
  union { short sh[8]; int4 v; } o;
#pragma unroll
  for (int j = 0; j < 8; ++j) {
    int d = lane * 8 + j;
    o.sh[j] = f2bf((xs[j] - mean) * rstd * gam[d] + bet[d]);
  }
  *(int4*)&h[row * D_DIM + lane * 8] = o.v;
}

// ---- m97-structure bf16 MFMA GEMM ----
// out[M,N] = A[M,K] @ Bt[N,K]^T + bias (+resid). 128x128 tile / block,
// 4 waves 2x2, each wave 64x64 = 4x4 16x16 frags. BK=32.
// Multi-output: column segment n0/nsplit selects {out,bias} (fused QKV).
// Each output buffer has row stride = nsplit.
template <int OUT_BF16, int RESID>
__global__ __launch_bounds__(256) void gemm128(
    const short* __restrict__ A, const short* __restrict__ Bt,
    const float* __restrict__ bias0, const float* __restrict__ bias1,
    const float* __restrict__ bias2,
    void* __restrict__ out0, void* __restrict__ out1, void* __restrict__ out2,
    const float* __restrict__ resid, int K, int nsplit) {
  __shared__ short As[128 * 32];
  __shared__ short Bs[128 * 32];
  const int t = threadIdx.x;
  const int wave = t >> 6, lane = t & 63;
  const int lr = lane & 15, g = lane >> 4;
  const int wr = wave >> 1, wc = wave & 1;
  const int m0 = blockIdx.y * 128, n0 = blockIdx.x * 128;

  const int seg = n0 / nsplit;                  // block-uniform
  const int ncol0 = n0 - seg * nsplit;
  const float* bias = seg == 0 ? bias0 : (seg == 1 ? bias1 : bias2);
  void* outp = seg == 0 ? out0 : (seg == 1 ? out1 : out2);

  // staging: 8 chunks of 1KB each for A and B; wave w owns chunks 2w, 2w+1.
  // chunk c = rows 16c..16c+15 (row = 64B). lane l -> byte c*1024 + l*16.
  const int crow = lane >> 2;                   // row within chunk
  const int ccol = (lane & 3) * 8;              // bf16 col within row

  f32x4 acc[4][4];
  const f32x4 vzero = {0.f, 0.f, 0.f, 0.f};
#pragma unroll
  for (int mi = 0; mi < 4; ++mi)
#pragma unroll
    for (int ni = 0; ni < 4; ++ni) acc[mi][ni] = vzero;

  for (int k0 = 0; k0 < K; k0 += 32) {
#pragma unroll
    for (int i = 0; i < 2; ++i) {
      const int c = wave * 2 + i;
      const int row = c * 16 + crow;
      __builtin_amdgcn_global_load_lds(
          (g_u32*)&A[(long)(m0 + row) * K + k0 + ccol],
          (lds_u32*)&As[c * 512], 16, 0, 0);
      __builtin_amdgcn_global_load_lds(
          (g_u32*)&Bt[(long)(n0 + row) * K + k0 + ccol],
          (lds_u32*)&Bs[c * 512], 16, 0, 0);
    }
    __syncthreads();
    bf16x8 af[4], bf[4];
#pragma unroll
    for (int mi = 0; mi < 4; ++mi)
      af[mi] = *(const bf16x8*)&As[(wr * 64 + mi * 16 + lr) * 32 + g * 8];
#pragma unroll
    for (int ni = 0; ni < 4; ++ni)
      bf[ni] = *(const bf16x8*)&Bs[(wc * 64 + ni * 16 + lr) * 32 + g * 8];
#pragma unroll
    for (int mi = 0; mi < 4; ++mi)
#pragma unroll
      for (int ni = 0; ni < 4; ++ni)
        acc[mi][ni] = __builtin_amdgcn_mfma_f32_16x16x32_bf16(af[mi], bf[ni], acc[mi][ni], 0, 0, 0);
    __syncthreads();
  }

  // C/D layout: col = lane&15, row = 4*(lane>>4) + reg
#pragma unroll
  for (int ni = 0; ni < 4; ++ni) {
    const int col = ncol0 + wc * 64 + ni * 16 + lr;
    const float bv = bias[col];
#pragma unroll
    for (int mi = 0; mi < 4; ++mi) {
#pragma unroll
      for (int r = 0; r < 4; ++r) {
        const long row = m0 + wr * 64 + mi * 16 + g * 4 + r;
        float val = acc[mi][ni][r] + bv;
        if (RESID) val += resid[row * (long)nsplit + col];
        if (OUT_BF16) ((short*)outp)[row * (long)nsplit + col] = f2bf(val);
        else          ((float*)outp)[row * (long)nsplit + col] = val;
      }
    }
  }
}

// ---- fused feature attention, one block per (b,e): 64 q-rows ----
__global__ __launch_bounds__(256) void attn_kernel(
    const short* __restrict__ q, const short* __restrict__ k,
    const short* __restrict__ v, const float* __restrict__ x,
    const float* __restrict__ wn_g, const float* __restrict__ wn_b,
    float* __restrict__ x1) {
  __shared__ float att_s[64][68];
  const int t = threadIdx.x;
  const int wave = t >> 6, lane = t & 63;
  const int lr = lane & 15, g = lane >> 4;
  const long base = (long)blockIdx.x * 64;
  const long qoff = base * D_DIM;

  const f32x4 vzero = {0.f, 0.f, 0.f, 0.f};
  f32x4 acc[4];
#pragma unroll
  for (int nt = 0; nt < 4; ++nt) acc[nt] = vzero;

  for (int ks = 0; ks < 16; ++ks) {
    const int kc = ks * 32 + g * 8;
    bf16x8 afr = *(const bf16x8*)&q[qoff + (long)(wave * 16 + lr) * D_DIM + kc];
#pragma unroll
    for (int nt = 0; nt < 4; ++nt) {
      bf16x8 bfr = *(const bf16x8*)&k[qoff + (long)(nt * 16 + lr) * D_DIM + kc];
      acc[nt] = __builtin_amdgcn_mfma_f32_16x16x32_bf16(afr, bfr, acc[nt], 0, 0, 0);
    }
  }

  const float scale = 0.044194173824159216f;  // 1/sqrt(512)
#pragma unroll
  for (int r = 0; r < 4; ++r) {
    float s = 0.f, ss = 0.f;
#pragma unroll
    for (int nt = 0; nt < 4; ++nt) { float e = acc[nt][r]; s += e; ss += e * e; }
#pragma unroll
    for (int m = 1; m < 16; m <<= 1) { s += __shfl_xor(s, m); ss += __shfl_xor(ss, m); }
    float mean = s * (1.f / 64);
    float var  = ss * (1.f / 64) - mean * mean;
    float rstd = rsqrtf(var + 1e-5f);
    float e[4]; float mx = -1e30f;
#pragma unroll
    for (int nt = 0; nt < 4; ++nt) {
      int col = nt * 16 + lr;
      e[nt] = ((acc[nt][r] - mean) * rstd * wn_g[col] + wn_b[col]) * scale;
      mx = fmaxf(mx, e[nt]);
    }
#pragma unroll
    for (int m = 1; m < 16; m <<= 1) mx = fmaxf(mx, __shfl_xor(mx, m));
    float se = 0.f;
#pragma unroll
    for (int nt = 0; nt < 4; ++nt) { e[nt] = expf(e[nt] - mx); se += e[nt]; }
#pragma unroll
    for (int m = 1; m < 16; m <<= 1) se += __shfl_xor(se, m);
    float inv = 1.f / se;
#pragma unroll
    for (int nt = 0; nt < 4; ++nt)
      att_s[wave * 16 + 4 * g + r][nt * 16 + lr] = e[nt] * inv;
  }
  __syncthreads();

  const int d0 = lane * 8;
  float accp[16][8];
#pragma unroll
  for (int qi = 0; qi < 16; ++qi)
#pragma unroll
    for (int j = 0; j < 8; ++j) accp[qi][j] = 0.f;

  for (int kk0 = 0; kk0 < 64; kk0 += 4) {
    float vf[4][8];
#pragma unroll
    for (int kc = 0; kc < 4; ++kc) {
      bf16x8 vv = *(const bf16x8*)&v[qoff + (long)(kk0 + kc) * D_DIM + d0];
#pragma unroll
      for (int j = 0; j < 8; ++j) vf[kc][j] = bf2f(vv[j]);
    }
#pragma unroll
    for (int qi = 0; qi < 16; ++qi) {
      float4 a4 = *(const float4*)&att_s[wave * 16 + qi][kk0];
#pragma unroll
      for (int j = 0; j < 8; ++j) {
        accp[qi][j] += a4.x * vf[0][j];
        accp[qi][j] += a4.y * vf[1][j];
        accp[qi][j] += a4.z * vf[2][j];
        accp[qi][j] += a4.w * vf[3][j];
      }
    }
  }
#pragma unroll
  for (int qi = 0; qi < 16; ++qi) {
    long row = base + wave * 16 + qi;
    const float* xr = x + row * D_DIM + d0;
    float* po = x1 + row * D_DIM + d0;
    float4 x0 = *(const float4*)xr;
    float4 xb = *(const float4*)(xr + 4);
    float4 o0, o1;
    o0.x = x0.x + accp[qi][0]; o0.y = x0.y + accp[qi][1];
    o0.z = x0.z + accp[qi][2]; o0.w = x0.w + accp[qi][3];
    o1.x = xb.x + accp[qi][4]; o1.y = xb.y + accp[qi][5];
    o1.z = xb.z + accp[qi][6]; o1.w = xb.w + accp[qi][7];
    *(float4*)po = o0;
    *(float4*)(po + 4) = o1;
  }
}

extern "C" void kernel_launch(void* const* d_in, const int* in_sizes, int n_in,
                              void* d_out, int out_size, void* d_ws, size_t ws_size,
                              hipStream_t stream) {
  (void)in_sizes; (void)n_in; (void)out_size; (void)ws_size;
  const float* x     = (const float*)d_in[0];
  const float* ln1_g = (const float*)d_in[1];
  const float* ln1_b = (const float*)d_in[2];
  const float* Wq    = (const float*)d_in[3];
  const float* bq    = (const float*)d_in[4];
  const float* Wk    = (const float*)d_in[5];
  const float* bk    = (const float*)d_in[6];
  const float* Wv    = (const float*)d_in[7];
  const float* bv    = (const float*)d_in[8];
  const float* wn_g  = (const float*)d_in[9];
  const float* wn_b  = (const float*)d_in[10];
  const float* ln2_g = (const float*)d_in[11];
  const float* ln2_b = (const float*)d_in[12];
  const float* W1    = (const float*)d_in[13];
  const float* b1    = (const float*)d_in[14];
  const float* W2    = (const float*)d_in[15];
  const float* b2    = (const float*)d_in[16];
  float* out = (float*)d_out;

  char* ws = (char*)d_ws;
  short* h   = (short*)(ws);                                  // 32 MB (h, then h2)
  short* qb  = (short*)(ws + (size_t)32  * 1024 * 1024);      // 32 MB
  short* kb  = (short*)(ws + (size_t)64  * 1024 * 1024);      // 32 MB
  short* vb  = (short*)(ws + (size_t)96  * 1024 * 1024);      // 32 MB
  short* ff1 = (short*)(ws + (size_t)32  * 1024 * 1024);      // 128 MB, aliases dead q/k/v
  short* Wqt = (short*)(ws + (size_t)160 * 1024 * 1024);      // [1536][512] contiguous qkv
  short* Wkt = Wqt + 512 * 512;
  short* Wvt = Wkt + 512 * 512;
  short* W1t = Wvt + 512 * 512;                               // [2048][512]
  short* W2t = W1t + 512 * 2048;                              // [512][2048]

  // weights -> bf16, transposed to [N][K]
  wconv_kernel<<<(512 * 512)  / 256, 256, 0, stream>>>(Wq, Wqt, 512, 512);
  wconv_kernel<<<(512 * 512)  / 256, 256, 0, stream>>>(Wk, Wkt, 512, 512);
  wconv_kernel<<<(512 * 512)  / 256, 256, 0, stream>>>(Wv, Wvt, 512, 512);
  wconv_kernel<<<(512 * 2048) / 256, 256, 0, stream>>>(W1, W1t, 512, 2048);
  wconv_kernel<<<(2048 * 512) / 256, 256, 0, stream>>>(W2, W2t, 2048, 512);

  ln_kernel<<<NROWS / 4, 256, 0, stream>>>(x, ln1_g, ln1_b, h);

  // fused QKV: N=1536 (Wqt/Wkt/Wvt contiguous), nsplit=512
  dim3 gqkv(1536 / 128, NROWS / 128);   // (12, 256)
  gemm128<1, 0><<<gqkv, 256, 0, stream>>>(h, Wqt, bq, bk, bv,
                                          qb, kb, vb, nullptr, 512, 512);

  attn_kernel<<<NBE, 256, 0, stream>>>(qb, kb, vb, x, wn_g, wn_b, out);

  ln_kernel<<<NROWS / 4, 256, 0, stream>>>(out, ln2_g, ln2_b, h);   // h2

  dim3 gff1(2048 / 128, NROWS / 128);   // (16, 256)
  gemm128<1, 0><<<gff1, 256, 0, stream>>>(h, W1t, b1, b1, b1,
                                          ff1, ff1, ff1, nullptr, 512, 2048);

  dim3 gff2(512 / 128, NROWS / 128);    // (4, 256)
  gemm128<0, 1><<<gff2, 256, 0, stream>>>(ff1, W2t, b2, b2, b2,
                                          out, out, out, out, 2048, 512);
}

// Round 3
// 571.745 us; speedup vs baseline: 1.2658x; 1.0614x over previous
//
#include <hip/hip_runtime.h>
#include <hip/hip_bf16.h>

// FeatureAttention on MI355X — Round 3: XCD-swizzled GEMMs, tiled wconv,
// LN2 fused into attn epilogue.
// B=32 E=16 F=64 D=512 EXP=4. Rows M = B*E*F = 32768.
// Pipeline: wconvT(x5) -> LN1 -> fused QKV GEMM -> attn(+LN2) -> FFN1 -> FFN2.

#define D_DIM 512
#define NROWS 32768
#define NBE   512

typedef __attribute__((ext_vector_type(8))) short bf16x8;
typedef __attribute__((ext_vector_type(4))) float f32x4;

typedef const __attribute__((address_space(1))) unsigned g_u32;
typedef __attribute__((address_space(3))) unsigned lds_u32;

__device__ __forceinline__ short f2bf(float f) {
  union { float f; unsigned u; } c; c.f = f;
  unsigned u = c.u;
  unsigned r = (u + 0x7FFFu + ((u >> 16) & 1u)) >> 16;   // RNE
  return (short)r;
}
__device__ __forceinline__ float bf2f(short s) {
  union { unsigned u; float f; } c; c.u = ((unsigned)(unsigned short)s) << 16;
  return c.f;
}

// ---- LDS-tiled transpose + fp32->bf16: Wt[n][k] = bf16(W[k][n]) ----
// 32x32 tile, coalesced reads AND writes. grid = (N/32, K/32).
__global__ __launch_bounds__(256) void wconvT(const float* __restrict__ W,
                                              short* __restrict__ Wt,
                                              int K, int N) {
  __shared__ float tile[32][33];
  const int t = threadIdx.x;
  const int r  = t >> 3;            // 0..31
  const int c4 = (t & 7) * 4;       // 0,4,...,28
  const long k0 = (long)blockIdx.y * 32;
  const long n0 = (long)blockIdx.x * 32;
  float4 v = *(const float4*)&W[(k0 + r) * N + n0 + c4];
  tile[r][c4 + 0] = v.x; tile[r][c4 + 1] = v.y;
  tile[r][c4 + 2] = v.z; tile[r][c4 + 3] = v.w;
  __syncthreads();
  union { short sh[4]; int2 v; } o;
#pragma unroll
  for (int j = 0; j < 4; ++j) o.sh[j] = f2bf(tile[c4 + j][r]);
  *(int2*)&Wt[(n0 + r) * K + k0 + c4] = o.v;
}

// ---- LayerNorm over D=512, fp32 in -> bf16 out. One wave per row. ----
__global__ __launch_bounds__(256) void ln_kernel(const float* __restrict__ x,
                                                 const float* __restrict__ gam,
                                                 const float* __restrict__ bet,
                                                 short* __restrict__ h) {
  const int t = threadIdx.x;
  const long row = (long)blockIdx.x * 4 + (t >> 6);
  const int lane = t & 63;
  const float* xr = x + row * D_DIM + lane * 8;
  float4 a = *(const float4*)xr;
  float4 b = *(const float4*)(xr + 4);
  float xs[8] = {a.x, a.y, a.z, a.w, b.x, b.y, b.z, b.w};
  float s = 0.f, ss = 0.f;
#pragma unroll
  for (int j = 0; j < 8; ++j) { s += xs[j]; ss += xs[j] * xs[j]; }
#pragma unroll
  for (int m = 1; m < 64; m <<= 1) {
    s  += __shfl_xor(s, m);
    ss += __shfl_xor(ss, m);
  }
  float mean = s * (1.f / D_DIM);
  float var  = ss * (1.f / D_DIM) - mean * mean;
  float rstd = rsqrtf(var + 1e-5f);
  union { short sh[8]; int4 v; } o;
#pragma unroll
  for (int j = 0; j < 8; ++j) {
    int d = lane * 8 + j;
    o.sh[j] = f2bf((xs[j] - mean) * rstd * gam[d] + bet[d]);
  }
  *(int4*)&h[row * D_DIM + lane * 8] = o.v;
}

// ---- m97-structure bf16 MFMA GEMM, XCD-chunked block swizzle ----
// out[M,N] = A[M,K] @ Bt[N,K]^T + bias (+resid). 128x128 tile / block,
// 4 waves 2x2, each wave 64x64 = 4x4 16x16 frags. BK=32.
// Multi-output: column segment n0/nsplit selects {out,bias} (fused QKV).
template <int OUT_BF16, int RESID>
__global__ __launch_bounds__(256) void gemm128(
    const short* __restrict__ A, const short* __restrict__ Bt,
    const float* __restrict__ bias0, const float* __restrict__ bias1,
    const float* __restrict__ bias2,
    void* __restrict__ out0, void* __restrict__ out1, void* __restrict__ out2,
    const float* __restrict__ resid, int K, int nsplit) {
  __shared__ short As[128 * 32];
  __shared__ short Bs[128 * 32];
  const int t = threadIdx.x;
  const int wave = t >> 6, lane = t & 63;
  const int lr = lane & 15, g = lane >> 4;
  const int wr = wave >> 1, wc = wave & 1;

  // XCD-chunked bijective swizzle (T1): hw dispatch round-robins bid%8 over
  // XCDs; remap so each XCD owns a contiguous lid chunk (N-tiles fastest ->
  // blocks sharing an A-panel land on the same XCD's L2). nwg % 8 == 0 here.
  const int gx = gridDim.x;
  const int nwg = gx * gridDim.y;
  const int hid = blockIdx.y * gx + blockIdx.x;
  const int lid = (hid & 7) * (nwg >> 3) + (hid >> 3);
  const int m0 = (lid / gx) * 128;
  const int n0 = (lid % gx) * 128;

  const int seg = n0 / nsplit;                  // block-uniform
  const int ncol0 = n0 - seg * nsplit;
  const float* bias = seg == 0 ? bias0 : (seg == 1 ? bias1 : bias2);
  void* outp = seg == 0 ? out0 : (seg == 1 ? out1 : out2);

  // staging: 8 chunks of 1KB each for A and B; wave w owns chunks 2w, 2w+1.
  const int crow = lane >> 2;                   // row within chunk
  const int ccol = (lane & 3) * 8;              // bf16 col within row

  f32x4 acc[4][4];
  const f32x4 vzero = {0.f, 0.f, 0.f, 0.f};
#pragma unroll
  for (int mi = 0; mi < 4; ++mi)
#pragma unroll
    for (int ni = 0; ni < 4; ++ni) acc[mi][ni] = vzero;

  for (int k0 = 0; k0 < K; k0 += 32) {
#pragma unroll
    for (int i = 0; i < 2; ++i) {
      const int c = wave * 2 + i;
      const int row = c * 16 + crow;
      __builtin_amdgcn_global_load_lds(
          (g_u32*)&A[(long)(m0 + row) * K + k0 + ccol],
          (lds_u32*)&As[c * 512], 16, 0, 0);
      __builtin_amdgcn_global_load_lds(
          (g_u32*)&Bt[(long)(n0 + row) * K + k0 + ccol],
          (lds_u32*)&Bs[c * 512], 16, 0, 0);
    }
    __syncthreads();
    bf16x8 af[4], bf[4];
#pragma unroll
    for (int mi = 0; mi < 4; ++mi)
      af[mi] = *(const bf16x8*)&As[(wr * 64 + mi * 16 + lr) * 32 + g * 8];
#pragma unroll
    for (int ni = 0; ni < 4; ++ni)
      bf[ni] = *(const bf16x8*)&Bs[(wc * 64 + ni * 16 + lr) * 32 + g * 8];
#pragma unroll
    for (int mi = 0; mi < 4; ++mi)
#pragma unroll
      for (int ni = 0; ni < 4; ++ni)
        acc[mi][ni] = __builtin_amdgcn_mfma_f32_16x16x32_bf16(af[mi], bf[ni], acc[mi][ni], 0, 0, 0);
    __syncthreads();
  }

  // C/D layout: col = lane&15, row = 4*(lane>>4) + reg
#pragma unroll
  for (int ni = 0; ni < 4; ++ni) {
    const int col = ncol0 + wc * 64 + ni * 16 + lr;
    const float bv = bias[col];
#pragma unroll
    for (int mi = 0; mi < 4; ++mi) {
#pragma unroll
      for (int r = 0; r < 4; ++r) {
        const long row = m0 + wr * 64 + mi * 16 + g * 4 + r;
        float val = acc[mi][ni][r] + bv;
        if (RESID) val += resid[row * (long)nsplit + col];
        if (OUT_BF16) ((short*)outp)[row * (long)nsplit + col] = f2bf(val);
        else          ((float*)outp)[row * (long)nsplit + col] = val;
      }
    }
  }
}

// ---- fused feature attention + residual + LN2, one block per (b,e) ----
// energy = q@k^T (MFMA), LN over keys, softmax/sqrt(D), PV (VALU),
// x1 = x + PV -> out (fp32), h2 = LN2(x1) -> bf16 (fused: rows complete here).
__global__ __launch_bounds__(256) void attn_kernel(
    const short* __restrict__ q, const short* __restrict__ k,
    const short* __restrict__ v, const float* __restrict__ x,
    const float* __restrict__ wn_g, const float* __restrict__ wn_b,
    const float* __restrict__ ln2_g, const float* __restrict__ ln2_b,
    float* __restrict__ x1, short* __restrict__ h2) {
  __shared__ float att_s[64][68];
  const int t = threadIdx.x;
  const int wave = t >> 6, lane = t & 63;
  const int lr = lane & 15, g = lane >> 4;
  const long base = (long)blockIdx.x * 64;
  const long qoff = base * D_DIM;

  const f32x4 vzero = {0.f, 0.f, 0.f, 0.f};
  f32x4 acc[4];
#pragma unroll
  for (int nt = 0; nt < 4; ++nt) acc[nt] = vzero;

  for (int ks = 0; ks < 16; ++ks) {
    const int kc = ks * 32 + g * 8;
    bf16x8 afr = *(const bf16x8*)&q[qoff + (long)(wave * 16 + lr) * D_DIM + kc];
#pragma unroll
    for (int nt = 0; nt < 4; ++nt) {
      bf16x8 bfr = *(const bf16x8*)&k[qoff + (long)(nt * 16 + lr) * D_DIM + kc];
      acc[nt] = __builtin_amdgcn_mfma_f32_16x16x32_bf16(afr, bfr, acc[nt], 0, 0, 0);
    }
  }

  const float scale = 0.044194173824159216f;  // 1/sqrt(512)
#pragma unroll
  for (int r = 0; r < 4; ++r) {
    float s = 0.f, ss = 0.f;
#pragma unroll
    for (int nt = 0; nt < 4; ++nt) { float e = acc[nt][r]; s += e; ss += e * e; }
#pragma unroll
    for (int m = 1; m < 16; m <<= 1) { s += __shfl_xor(s, m); ss += __shfl_xor(ss, m); }
    float mean = s * (1.f / 64);
    float var  = ss * (1.f / 64) - mean * mean;
    float rstd = rsqrtf(var + 1e-5f);
    float e[4]; float mx = -1e30f;
#pragma unroll
    for (int nt = 0; nt < 4; ++nt) {
      int col = nt * 16 + lr;
      e[nt] = ((acc[nt][r] - mean) * rstd * wn_g[col] + wn_b[col]) * scale;
      mx = fmaxf(mx, e[nt]);
    }
#pragma unroll
    for (int m = 1; m < 16; m <<= 1) mx = fmaxf(mx, __shfl_xor(mx, m));
    float se = 0.f;
#pragma unroll
    for (int nt = 0; nt < 4; ++nt) { e[nt] = expf(e[nt] - mx); se += e[nt]; }
#pragma unroll
    for (int m = 1; m < 16; m <<= 1) se += __shfl_xor(se, m);
    float inv = 1.f / se;
#pragma unroll
    for (int nt = 0; nt < 4; ++nt)
      att_s[wave * 16 + 4 * g + r][nt * 16 + lr] = e[nt] * inv;
  }
  __syncthreads();

  // PV: wave w handles q-rows w*16..w*16+15; lane owns d0 = lane*8
  const int d0 = lane * 8;
  float accp[16][8];
#pragma unroll
  for (int qi = 0; qi < 16; ++qi)
#pragma unroll
    for (int j = 0; j < 8; ++j) accp[qi][j] = 0.f;

  for (int kk0 = 0; kk0 < 64; kk0 += 4) {
    float vf[4][8];
#pragma unroll
    for (int kc = 0; kc < 4; ++kc) {
      bf16x8 vv = *(const bf16x8*)&v[qoff + (long)(kk0 + kc) * D_DIM + d0];
#pragma unroll
      for (int j = 0; j < 8; ++j) vf[kc][j] = bf2f(vv[j]);
    }
#pragma unroll
    for (int qi = 0; qi < 16; ++qi) {
      float4 a4 = *(const float4*)&att_s[wave * 16 + qi][kk0];
#pragma unroll
      for (int j = 0; j < 8; ++j) {
        accp[qi][j] += a4.x * vf[0][j];
        accp[qi][j] += a4.y * vf[1][j];
        accp[qi][j] += a4.z * vf[2][j];
        accp[qi][j] += a4.w * vf[3][j];
      }
    }
  }

  // ln2 gamma/beta slice for this lane (same for all 16 rows)
  float g2v[8], b2v[8];
#pragma unroll
  for (int j = 0; j < 8; ++j) { g2v[j] = ln2_g[d0 + j]; b2v[j] = ln2_b[d0 + j]; }

#pragma unroll
  for (int qi = 0; qi < 16; ++qi) {
    const long row = base + wave * 16 + qi;
    const float* xr = x + row * D_DIM + d0;
    float4 x0 = *(const float4*)xr;
    float4 xb = *(const float4*)(xr + 4);
    accp[qi][0] += x0.x; accp[qi][1] += x0.y;
    accp[qi][2] += x0.z; accp[qi][3] += x0.w;
    accp[qi][4] += xb.x; accp[qi][5] += xb.y;
    accp[qi][6] += xb.z; accp[qi][7] += xb.w;
    float* po = x1 + row * D_DIM + d0;
    *(float4*)po       = make_float4(accp[qi][0], accp[qi][1], accp[qi][2], accp[qi][3]);
    *(float4*)(po + 4) = make_float4(accp[qi][4], accp[qi][5], accp[qi][6], accp[qi][7]);
    // fused LN2 over the complete row (64 lanes x 8)
    float s = 0.f, ss = 0.f;
#pragma unroll
    for (int j = 0; j < 8; ++j) { s += accp[qi][j]; ss += accp[qi][j] * accp[qi][j]; }
#pragma unroll
    for (int m = 1; m < 64; m <<= 1) { s += __shfl_xor(s, m); ss += __shfl_xor(ss, m); }
    float mean = s * (1.f / D_DIM);
    float var  = ss * (1.f / D_DIM) - mean * mean;
    float rstd = rsqrtf(var + 1e-5f);
    union { short sh[8]; int4 v; } o;
#pragma unroll
    for (int j = 0; j < 8; ++j)
      o.sh[j] = f2bf((accp[qi][j] - mean) * rstd * g2v[j] + b2v[j]);
    *(int4*)&h2[row * D_DIM + d0] = o.v;
  }
}

extern "C" void kernel_launch(void* const* d_in, const int* in_sizes, int n_in,
                              void* d_out, int out_size, void* d_ws, size_t ws_size,
                              hipStream_t stream) {
  (void)in_sizes; (void)n_in; (void)out_size; (void)ws_size;
  const float* x     = (const float*)d_in[0];
  const float* ln1_g = (const float*)d_in[1];
  const float* ln1_b = (const float*)d_in[2];
  const float* Wq    = (const float*)d_in[3];
  const float* bq    = (const float*)d_in[4];
  const float* Wk    = (const float*)d_in[5];
  const float* bk    = (const float*)d_in[6];
  const float* Wv    = (const float*)d_in[7];
  const float* bv    = (const float*)d_in[8];
  const float* wn_g  = (const float*)d_in[9];
  const float* wn_b  = (const float*)d_in[10];
  const float* ln2_g = (const float*)d_in[11];
  const float* ln2_b = (const float*)d_in[12];
  const float* W1    = (const float*)d_in[13];
  const float* b1    = (const float*)d_in[14];
  const float* W2    = (const float*)d_in[15];
  const float* b2    = (const float*)d_in[16];
  float* out = (float*)d_out;

  char* ws = (char*)d_ws;
  short* h   = (short*)(ws);                                  // 32 MB (h, then h2)
  short* qb  = (short*)(ws + (size_t)32  * 1024 * 1024);      // 32 MB
  short* kb  = (short*)(ws + (size_t)64  * 1024 * 1024);      // 32 MB
  short* vb  = (short*)(ws + (size_t)96  * 1024 * 1024);      // 32 MB
  short* ff1 = (short*)(ws + (size_t)32  * 1024 * 1024);      // 128 MB, aliases dead q/k/v
  short* Wqt = (short*)(ws + (size_t)160 * 1024 * 1024);      // [1536][512] contiguous qkv
  short* Wkt = Wqt + 512 * 512;
  short* Wvt = Wkt + 512 * 512;
  short* W1t = Wvt + 512 * 512;                               // [2048][512]
  short* W2t = W1t + 512 * 2048;                              // [512][2048]

  // weights -> bf16, transposed to [N][K] (tiled, coalesced both sides)
  wconvT<<<dim3(512 / 32, 512 / 32),  256, 0, stream>>>(Wq, Wqt, 512, 512);
  wconvT<<<dim3(512 / 32, 512 / 32),  256, 0, stream>>>(Wk, Wkt, 512, 512);
  wconvT<<<dim3(512 / 32, 512 / 32),  256, 0, stream>>>(Wv, Wvt, 512, 512);
  wconvT<<<dim3(2048 / 32, 512 / 32), 256, 0, stream>>>(W1, W1t, 512, 2048);
  wconvT<<<dim3(512 / 32, 2048 / 32), 256, 0, stream>>>(W2, W2t, 2048, 512);

  ln_kernel<<<NROWS / 4, 256, 0, stream>>>(x, ln1_g, ln1_b, h);

  // fused QKV: N=1536 (Wqt/Wkt/Wvt contiguous), nsplit=512
  dim3 gqkv(1536 / 128, NROWS / 128);   // (12, 256) = 3072 blocks
  gemm128<1, 0><<<gqkv, 256, 0, stream>>>(h, Wqt, bq, bk, bv,
                                          qb, kb, vb, nullptr, 512, 512);

  attn_kernel<<<NBE, 256, 0, stream>>>(qb, kb, vb, x, wn_g, wn_b,
                                       ln2_g, ln2_b, out, h);

  dim3 gff1(2048 / 128, NROWS / 128);   // (16, 256) = 4096 blocks
  gemm128<1, 0><<<gff1, 256, 0, stream>>>(h, W1t, b1, b1, b1,
                                          ff1, ff1, ff1, nullptr, 512, 2048);

  dim3 gff2(512 / 128, NROWS / 128);    // (4, 256) = 1024 blocks
  gemm128<0, 1><<<gff2, 256, 0, stream>>>(ff1, W2t, b2, b2, b2,
                                          out, out, out, out, 2048, 512);
}